// Round 13
// baseline (21.285 us; speedup 1.0000x reference)
//
#include <hip/hip_runtime.h>
#include <hip/hip_bf16.h>

typedef __attribute__((ext_vector_type(4)))  int      int4v;
typedef __attribute__((ext_vector_type(16))) int      i32x16;
typedef __attribute__((ext_vector_type(4)))  unsigned uint4v;

#define K_DIM    4096
#define N_DIM    16384
#define WORDS_N  512
#define XSCALE   24.0f
#define INV_XS   (1.0f / 24.0f)

// ---------------- P: BYTE-transpose planes -> PT + quantize x ----------------
// PT dword index = (kbl*2048 + g)*16 + plane*8 + d, where g = wc*4 + c.
// Byte i of that dword = byte c of W_plane[k = kbl*32 + 4d + i][wc].
// (bit-level transpose is deferred into gemm's decode, where it is free)
// xq[(kbl*2 + h)*32 + bl] : 16 bytes = i8(round(24*x[bl][kbl*32 + h*16 + i])).
__global__ __launch_bounds__(512, 4)
void prep(const unsigned* __restrict__ Bnz,
          const unsigned* __restrict__ Bsg,
          const float* __restrict__ x32,
          unsigned* __restrict__ PT,
          uint4v* __restrict__ xq)
{
    __shared__ unsigned sm[2][32][65];   // 16.6 KB

    const int bid = blockIdx.x;          // 1024 = 128 kbl x 8 wcpan
    const int t   = threadIdx.x;

    // x quantize role: 8 entries/block (8192 total)
    if (t < 8) {
        const int e   = bid * 8 + t;
        const int bl  = e & 31;
        const int hh  = (e >> 5) & 1;
        const int kbl = e >> 6;                  // 0..127
        const float* src = x32 + (size_t)bl * K_DIM + kbl * 32 + hh * 16;
        uint4v w;
        #pragma unroll
        for (int g = 0; g < 4; ++g) {
            const float4 v = *(const float4*)(src + g * 4);
            const int i0 = __float2int_rn(fminf(fmaxf(v.x * XSCALE, -127.f), 127.f));
            const int i1 = __float2int_rn(fminf(fmaxf(v.y * XSCALE, -127.f), 127.f));
            const int i2 = __float2int_rn(fminf(fmaxf(v.z * XSCALE, -127.f), 127.f));
            const int i3 = __float2int_rn(fminf(fmaxf(v.w * XSCALE, -127.f), 127.f));
            const unsigned p01 = __builtin_amdgcn_perm((unsigned)i1, (unsigned)i0, 0x00000400u);
            const unsigned p23 = __builtin_amdgcn_perm((unsigned)i3, (unsigned)i2, 0x00000400u);
            w[g] = __builtin_amdgcn_perm(p23, p01, 0x05040100u);
        }
        xq[e] = w;
    }

    const int kbl  = bid >> 3;           // 0..127 (32 k each)
    const int wcp0 = (bid & 7) * 64;     // word-col group == gemm's XCD group

    // stage 32 k x 64 wc words for BOTH planes, coalesced: 4 words/thread/plane
    {
        const int r  = t >> 4;           // 0..31
        const int c0 = (t & 15) * 4;
        const unsigned* s0 = Bnz + (size_t)(kbl * 32 + r) * WORDS_N + wcp0 + c0;
        uint4v v0 = *(const uint4v*)s0;
        sm[0][r][c0+0]=v0[0]; sm[0][r][c0+1]=v0[1]; sm[0][r][c0+2]=v0[2]; sm[0][r][c0+3]=v0[3];
        const unsigned* s1 = Bsg + (size_t)(kbl * 32 + r) * WORDS_N + wcp0 + c0;
        uint4v w0 = *(const uint4v*)s1;
        sm[1][r][c0+0]=w0[0]; sm[1][r][c0+1]=w0[1]; sm[1][r][c0+2]=w0[2]; sm[1][r][c0+3]=w0[3];
    }
    __syncthreads();

    const int lane = t & 63;
    const int wv   = t >> 6;
    const int half = lane >> 5;
    const int j    = lane & 31;
    // staged-row swizzle: lane j reads W[k = 4*(j&7) + (j>>3)] so that after
    // byte-butterfly {8,16}, lane j byte m = byte (j>>3) of W[4*(j&7)+m].
    const int rs   = 4 * (j & 7) + (j >> 3);   // distinct 0..31 -> conflict-free

    const unsigned sel8  = (lane & 8)  ? 0x07030501u : 0x02060004u;
    const unsigned sel16 = (lane & 16) ? 0x07060302u : 0x01000504u;

    auto bt = [&](unsigned xw) -> unsigned {
        unsigned y = __shfl_xor(xw, 8, 64);
        xw = __builtin_amdgcn_perm(xw, y, sel8);
        y = __shfl_xor(xw, 16, 64);
        return __builtin_amdgcn_perm(xw, y, sel16);
    };

    // 4 wcl tasks/thread x 2 planes; out lane j = (c = j>>3, d = j&7)
    #pragma unroll
    for (int i = 0; i < 4; ++i) {
        const int wcl = wv * 8 + half * 4 + i;
        const unsigned onz = bt(sm[0][rs][wcl]);
        const unsigned osg = bt(sm[1][rs][wcl]);
        const size_t base = ((size_t)kbl * 2048 +
                             (size_t)(wcp0 + wcl) * 4 + (j >> 3)) * 16 + (j & 7);
        PT[base]     = onz;
        PT[base + 8] = osg;
    }
}

// ---------------- G: i8 GEMM with in-decode bit extraction -------------------
__global__ __launch_bounds__(512, 4)
void gemm_fused(const int4v* __restrict__ xq,
                const unsigned* __restrict__ PT,
                const float* __restrict__ bias,
                float* __restrict__ out)
{
    __shared__ int red[8][1024];               // 32 KB: 8 partial 32x32 tiles

    const int bid = blockIdx.x;                // 512 blocks, one word-column each
    const int wc  = (bid & 7) * 64 + (bid >> 3);    // XCD = bid&7 = wc>>6
    const int n0  = wc * 32;
    const int tid = threadIdx.x;
    const int lane = tid & 63;
    const int wv   = tid >> 6;                 // wave owns k-range [wv*512, +512)
    const int h    = lane >> 5;
    const int bl   = lane & 31;
    const int sh   = bl & 7;                   // bit position within byte-plane

    const int kblk0 = wv * 16;
    const unsigned* pp = PT + ((size_t)kblk0 * 2048 +
                               (size_t)wc * 4 + (bl >> 3)) * 16 + h * 4;
    // per-kbl stride = 2048*16 dwords = 32768

    i32x16 acc{};

    uint4v cn0, cs0, cn1, cs1;                 // byte-planes for the 2 kbl of chunk

    cn0 = *(const uint4v*)(pp);
    cs0 = *(const uint4v*)(pp + 8);
    cn1 = *(const uint4v*)(pp + 32768);
    cs1 = *(const uint4v*)(pp + 32768 + 8);

    const unsigned K1 = 0x01010101u, POOL = 0xFF000100u;

    #pragma unroll
    for (int c = 0; c < 8; ++c) {
        uint4v pn0{}, ps0{}, pn1{}, ps1{};
        if (c + 1 < 8) {                       // issue next-chunk loads early
            const unsigned* q = pp + (size_t)(2 * c + 2) * 32768;
            pn0 = *(const uint4v*)(q);
            ps0 = *(const uint4v*)(q + 8);
            pn1 = *(const uint4v*)(q + 32768);
            ps1 = *(const uint4v*)(q + 32768 + 8);
        }
        const int ke = kblk0 + 2 * c;
        int4v cae = xq[((ke + 0) * 2 + h) * 32 + bl];
        int4v cao = xq[((ke + 1) * 2 + h) * 32 + bl];

        union { unsigned u[4]; int4v v; } bb;
        #pragma unroll
        for (int dd = 0; dd < 4; ++dd) {
            const unsigned ttv = (cn0[dd] >> sh) & K1;
            const unsigned uuv = (cs0[dd] >> sh) & K1;
            bb.u[dd] = __builtin_amdgcn_perm(POOL, POOL, ttv | (uuv << 1));
        }
        acc = __builtin_amdgcn_mfma_i32_32x32x32_i8(cae, bb.v, acc, 0, 0, 0);
        #pragma unroll
        for (int dd = 0; dd < 4; ++dd) {
            const unsigned ttv = (cn1[dd] >> sh) & K1;
            const unsigned uuv = (cs1[dd] >> sh) & K1;
            bb.u[dd] = __builtin_amdgcn_perm(POOL, POOL, ttv | (uuv << 1));
        }
        acc = __builtin_amdgcn_mfma_i32_32x32x32_i8(cao, bb.v, acc, 0, 0, 0);

        cn0 = pn0; cs0 = ps0; cn1 = pn1; cs1 = ps1;
    }

    // Per-wave partial tile -> LDS (i32, exact).
    // C/D layout: col = lane&31, row = (r&3) + 8*(r>>2) + 4*(lane>>5)
    #pragma unroll
    for (int r = 0; r < 16; ++r) {
        const int row = (r & 3) + 8 * (r >> 2) + 4 * h;
        red[wv][row * 32 + bl] = acc[r];
    }
    __syncthreads();

    // 8-way K reduction (exact i32) + scale + bias + ReLU + fp32 store.
    const int i0 = tid * 2;
    int sx = 0, sy = 0;
    #pragma unroll
    for (int s = 0; s < 8; ++s) {
        const int2 p = *(const int2*)&red[s][i0];
        sx += p.x;
        sy += p.y;
    }
    const int m  = tid >> 4;            // output row 0..31
    const int nn = i0 & 31;             // even column within tile
    const float2 bv = *(const float2*)(bias + n0 + nn);
    float2 y;
    y.x = (float)sx * INV_XS + bv.x; y.x = y.x < 0.f ? 0.f : y.x;
    y.y = (float)sy * INV_XS + bv.y; y.y = y.y < 0.f ? 0.f : y.y;
    *(float2*)(out + (size_t)m * N_DIM + n0 + nn) = y;
}

extern "C" void kernel_launch(void* const* d_in, const int* in_sizes, int n_in,
                              void* d_out, int out_size, void* d_ws, size_t ws_size,
                              hipStream_t stream) {
    const float* x32    = (const float*)d_in[0];      // fp32 [32][4096]
    const unsigned* nz  = (const unsigned*)d_in[1];
    const unsigned* sg  = (const unsigned*)d_in[2];
    const float* bias   = (const float*)d_in[3];
    float* out          = (float*)d_out;

    // ws: [0,16M) PT byte-planes ; [16M,+128K) xq (i8 A fragments)
    char* ws = (char*)d_ws;
    unsigned* PT = (unsigned*)ws;
    uint4v*   xq = (uint4v*)(ws + (size_t)16 * 1024 * 1024);

    prep<<<1024, 512, 0, stream>>>(nz, sg, x32, PT, xq);
    gemm_fused<<<512, 512, 0, stream>>>((const int4v*)xq, PT, bias, out);
}